// Round 13
// baseline (67.900 us; speedup 1.0000x reference)
//
#include <hip/hip_runtime.h>
#include <hip/hip_bf16.h>
#include <math.h>

#define LA 1536
#define LS 512
#define LT 2048
#define CC 256
#define NH 4
#define DKH 64
#define NB 4
#define NT (LT / 64)
#define NTA (LA / 64)     // 24 audio tiles
#define SZ ((size_t)NB * LT * CC)

// (1/sqrt(64)) * log2(e): softmax runs in exp2 domain, folded into Q
#define QSCALE 0.1803368801111244f

typedef _Float16 f16;
typedef __attribute__((ext_vector_type(8))) _Float16 f16x8;
typedef __attribute__((ext_vector_type(4))) _Float16 f16x4;
typedef __attribute__((ext_vector_type(4))) float f32x4;
typedef __attribute__((ext_vector_type(16))) float f32x16;

__device__ inline f16x8 cvt8(const float4 a, const float4 b) {
    f16x8 h;
    h[0] = (_Float16)a.x; h[1] = (_Float16)a.y; h[2] = (_Float16)a.z; h[3] = (_Float16)a.w;
    h[4] = (_Float16)b.x; h[5] = (_Float16)b.y; h[6] = (_Float16)b.z; h[7] = (_Float16)b.w;
    return h;
}

// sigma = swap bits 2 and 3 (involution). Storing K row k at LDS row SIG(k)
// makes the swapped-QK^T C-registers line up exactly with the PV B-fragment
// k-order (HW-verified rounds 8 & 11: passed with identical absmax).
#define SIG(j) (((j) & ~12) | (((j) & 4) << 1) | (((j) & 8) >> 1))

// ---------------------------------------------------------------------------
// Kernel 1: fused QKV projection, fp16 MFMA (16x16x32), 128x64 tiles.
// Q gets QSCALE folded in. V transposed Vt[(b*NH+h)*DKH+d][l] via LDS.
// (R11 verbatim)
// ---------------------------------------------------------------------------
__global__ __launch_bounds__(256) void qkv_mfma(
    const float* __restrict__ audio, const float* __restrict__ text,
    const float* __restrict__ Wq, const float* __restrict__ bq,
    const float* __restrict__ Wk, const float* __restrict__ bk,
    const float* __restrict__ Wv, const float* __restrict__ bv,
    f16* __restrict__ Qh, f16* __restrict__ Kh, f16* __restrict__ Vth)
{
    __shared__ f16 smem[128 * 64 + 64 * 64];
    f16* As = smem;
    f16* Bs = smem + 128 * 64;

    const int tid = threadIdx.x;
    const int w = tid >> 6, l = tid & 63;
    const int g = l >> 4, r = l & 15;

    const int m0 = blockIdx.x * 128;
    const int n0 = blockIdx.y * 64;
    const int mat = n0 >> 8;          // 0=Q 1=K 2=V
    const int ch0 = n0 & 255;

    const float* W    = (mat == 0) ? Wq : (mat == 1) ? Wk : Wv;
    const float* bias = (mat == 0) ? bq : (mat == 1) ? bk : bv;

    const int b  = m0 >> 11;
    const int l0 = m0 & 2047;

    f32x4 acc[2][4] = {};

    for (int k0 = 0; k0 < CC; k0 += 64) {
        #pragma unroll
        for (int m = 0; m < 4; ++m) {
            const int idx = m * 256 + tid;
            const int row = idx >> 3, c = idx & 7;
            const int lrow = l0 + row;
            const float* src = (lrow < LA)
                ? (audio + ((size_t)b * LA + lrow) * CC + k0 + c * 8)
                : (text  + ((size_t)b * LS + (lrow - LA)) * CC + k0 + c * 8);
            const float4 x0 = *(const float4*)src;
            const float4 x1 = *(const float4*)(src + 4);
            *(f16x8*)(As + row * 64 + ((c ^ (row & 7)) << 3)) = cvt8(x0, x1);
        }
        #pragma unroll
        for (int m = 0; m < 2; ++m) {
            const int idx = m * 256 + tid;
            const int row = idx >> 3, c = idx & 7;
            const float* src = W + (size_t)(ch0 + row) * CC + k0 + c * 8;
            const float4 x0 = *(const float4*)src;
            const float4 x1 = *(const float4*)(src + 4);
            *(f16x8*)(Bs + row * 64 + ((c ^ (row & 7)) << 3)) = cvt8(x0, x1);
        }
        __syncthreads();
        #pragma unroll
        for (int kc = 0; kc < 2; ++kc) {
            f16x8 af[2];
            #pragma unroll
            for (int i = 0; i < 2; ++i) {
                const int row = w * 32 + i * 16 + r;
                const int c = kc * 4 + g;
                af[i] = *(const f16x8*)(As + row * 64 + ((c ^ (row & 7)) << 3));
            }
            f16x8 bf[4];
            #pragma unroll
            for (int j = 0; j < 4; ++j) {
                const int row = j * 16 + r;
                const int c = kc * 4 + g;
                bf[j] = *(const f16x8*)(Bs + row * 64 + ((c ^ (row & 7)) << 3));
            }
            #pragma unroll
            for (int i = 0; i < 2; ++i)
                #pragma unroll
                for (int j = 0; j < 4; ++j)
                    acc[i][j] = __builtin_amdgcn_mfma_f32_16x16x32_f16(af[i], bf[j], acc[i][j], 0, 0, 0);
        }
        __syncthreads();
    }

    float bcol[4];
    #pragma unroll
    for (int j = 0; j < 4; ++j) bcol[j] = bias[ch0 + j * 16 + r];

    if (mat <= 1) {
        f16* Out = (mat == 0) ? Qh : Kh;
        const float osc = (mat == 0) ? QSCALE : 1.0f;
        #pragma unroll
        for (int i = 0; i < 2; ++i)
            #pragma unroll
            for (int e = 0; e < 4; ++e) {
                const int m = m0 + w * 32 + i * 16 + g * 4 + e;
                #pragma unroll
                for (int j = 0; j < 4; ++j)
                    Out[(size_t)m * CC + ch0 + j * 16 + r] =
                        (_Float16)((acc[i][j][e] + bcol[j]) * osc);
            }
    } else {
        // V: stage C^T in LDS (Ts[64 n][136 m-pad]), then coalesced vec8 store.
        f16* Ts = smem;
        #pragma unroll
        for (int i = 0; i < 2; ++i)
            #pragma unroll
            for (int e = 0; e < 4; ++e) {
                const int ml = w * 32 + i * 16 + g * 4 + e;
                #pragma unroll
                for (int j = 0; j < 4; ++j)
                    Ts[(j * 16 + r) * 136 + ml] = (_Float16)(acc[i][j][e] + bcol[j]);
            }
        __syncthreads();
        const int b2 = m0 >> 11, l0m = m0 & 2047;
        #pragma unroll
        for (int u = 0; u < 4; ++u) {
            const int idx = u * 256 + tid;
            const int nl = idx >> 4, mc = idx & 15;
            const f16x8 vv = *(const f16x8*)(Ts + nl * 136 + mc * 8);
            const int nglob = ch0 + nl;
            const int hh = nglob >> 6, dd = nglob & 63;
            *(f16x8*)(Vth + ((size_t)((b2 * NH + hh) * DKH + dd)) * LT + l0m + mc * 8) = vv;
        }
    }
}

// ---------------------------------------------------------------------------
// Kernel 2: flash attention, 32x32x16 MFMA (R11 verbatim) + XCD-AWARE REMAP.
// Flat 1-D grid of 512: cmb = flat & 15 selects (b,h) (fastest -> same-combo
// blocks land on one XCD under d%8 round-robin; 2 combos/XCD = 1 MB K/V in
// each 4 MB L2), q-tile = flat >> 4. R11 measured 74 MB FETCH (~5x refetch)
// with the old x-fastest mapping - this is the isolated fix.
// 512 thr = 4 tile-split groups x 2 waves x 32 q; 16 waves/CU; single K/V
// buffer per group; reg-staged next tile; lane owns ONE q-row (1-shfl
// reduces, lane-local sc/inv); SIG keeps P in registers; exp2 softmax,
// exact defer-rescale, tile skips; 4-way merge over dead K/V LDS.
// ---------------------------------------------------------------------------
__global__ __launch_bounds__(512, 4) void attn_f16(
    const f16* __restrict__ Q, const f16* __restrict__ K,
    const f16* __restrict__ Vt,
    const int* __restrict__ slen, const int* __restrict__ tlen,
    f16* __restrict__ AO)
{
    __shared__ __align__(16) f16 smem[8 * 4096];   // Ks[4] | Vts[4]; merge overlay

    const int tid = threadIdx.x;
    const int w = tid >> 6, l = tid & 63;
    const int gid = w >> 1, qh = w & 1;
    const int lo = l & 31, hi = l >> 5;

    // ---- XCD-aware remap: (b,h) combo fastest, q-tile slowest
    const int flat = blockIdx.x;
    const int cmb  = flat & 15;
    const int q0   = (flat >> 4) * 64;
    const int h    = cmb & 3;
    const int b    = cmb >> 2;

    const int ilen = slen[b];
    const int kcap = LA + tlen[b];
    const int nskip = ilen >> 6;
    int ntskip = 0;
    if (q0 >= LA) {
        const int skipmax = min(q0 - 63, kcap - 64);
        const int d = skipmax - LA;
        ntskip = (d < 0) ? 0 : ((d >> 6) + 1);
    }
    const int nAudio = NTA - nskip;                  // >= 1
    const int nProc  = nAudio + (NT - NTA) - ntskip; // >= 1
    const int nIter  = (nProc + 3) >> 2;

    const int qrow = q0 + 32 * qh + lo;

    // Q B-fragments (QSCALE pre-folded): lane holds Q[qrow][16c + 8hi + e]
    f16x8 qf[4];
    #pragma unroll
    for (int c = 0; c < 4; ++c)
        qf[c] = *(const f16x8*)(Q + ((size_t)(b * LT) + qrow) * CC + h * DKH + 16 * c + 8 * hi);

    // staging: group's 2 waves cover 64 rows: t 0..3, sr = 8*(4*qh+t) + (l>>3)
    const int srw = l >> 3, scc = l & 7;
    f16* Ks  = smem + gid * 4096;
    f16* Vts = smem + 16384 + gid * 4096;

    #define TILE_OF(p) ((p) < nAudio ? (nskip + (p)) : (NTA + ntskip + ((p) - nAudio)))

    if (gid < nProc) {   // prologue: stage this group's first tile
        const int k0 = TILE_OF(gid) * 64;
        #pragma unroll
        for (int t = 0; t < 4; ++t) {
            const int sr = 8 * (4 * qh + t) + srw;
            const int kr = SIG(sr);
            *(f16x8*)(Ks + kr * 64 + ((scc ^ (kr & 7)) << 3)) =
                *(const f16x8*)(K + ((size_t)(b * LT) + k0 + sr) * CC + h * DKH + scc * 8);
            *(f16x8*)(Vts + sr * 64 + ((scc ^ (sr & 7)) << 3)) =
                *(const f16x8*)(Vt + ((size_t)((b * NH + h) * DKH) + sr) * LT + k0 + scc * 8);
        }
    }

    float m_run = -1e30f, l_run = 0.0f;
    f32x16 o[2] = {};

    for (int i = 0; i < nIter; ++i) {
        __syncthreads();                 // A: staged tiles visible
        const int pcur = 4 * i + gid;
        const bool curV = pcur < nProc;
        const bool nxtV = (pcur + 4) < nProc;

        f16x8 kreg[4], vreg[4];
        if (nxtV) {                      // issue next-tile loads early
            const int kn = TILE_OF(pcur + 4) * 64;
            #pragma unroll
            for (int t = 0; t < 4; ++t) {
                const int sr = 8 * (4 * qh + t) + srw;
                kreg[t] = *(const f16x8*)(K + ((size_t)(b * LT) + kn + sr) * CC + h * DKH + scc * 8);
                vreg[t] = *(const f16x8*)(Vt + ((size_t)((b * NH + h) * DKH) + sr) * LT + kn + scc * 8);
            }
        }

        if (curV) {
            const int kt = TILE_OF(pcur);
            const int k0 = kt * 64;

            // ---- S^T = K . Q^T  (two 32-key halves; K rows SIG-permuted)
            f32x16 s0 = {}, s1 = {};
            #pragma unroll
            for (int c = 0; c < 4; ++c) {
                const int cc = 2 * c + hi;
                const int r0 = lo;
                const f16x8 a0 = *(const f16x8*)(Ks + r0 * 64 + ((cc ^ (r0 & 7)) << 3));
                s0 = __builtin_amdgcn_mfma_f32_32x32x16_f16(a0, qf[c], s0, 0, 0, 0);
                const int r1 = 32 + lo;
                const f16x8 a1 = *(const f16x8*)(Ks + r1 * 64 + ((cc ^ (r1 & 7)) << 3));
                s1 = __builtin_amdgcn_mfma_f32_32x32x16_f16(a1, qf[c], s1, 0, 0, 0);
            }

            // ---- mask. key(reg) = k0 + 16*((reg>>3)&1) + 8hi + 4*((reg>>2)&1) + (reg&3)
            const int mode = (kt < NTA) ? ((k0 >= ilen) ? 0 : 1)
                                        : ((q0 < LA) ? 0 : 2);
            if (mode == 1) {
                #pragma unroll
                for (int reg = 0; reg < 16; ++reg) {
                    const int kk0 = k0 + 16 * ((reg >> 3) & 1) + 8 * hi + 4 * ((reg >> 2) & 1) + (reg & 3);
                    if (kk0 < ilen)      s0[reg] = -INFINITY;
                    if (kk0 + 32 < ilen) s1[reg] = -INFINITY;
                }
            } else if (mode == 2) {
                #pragma unroll
                for (int reg = 0; reg < 16; ++reg) {
                    const int kk0 = k0 + 16 * ((reg >> 3) & 1) + 8 * hi + 4 * ((reg >> 2) & 1) + (reg & 3);
                    if (!(kk0 > qrow || kk0 >= kcap))      s0[reg] = -INFINITY;
                    const int kk1 = kk0 + 32;
                    if (!(kk1 > qrow || kk1 >= kcap))      s1[reg] = -INFINITY;
                }
            }

            // ---- online softmax (exp2 domain, finite sentinel, 1-shfl reduce)
            float mloc = -1e30f;
            #pragma unroll
            for (int reg = 0; reg < 16; ++reg) {
                mloc = fmaxf(mloc, s0[reg]);
                mloc = fmaxf(mloc, s1[reg]);
            }
            mloc = fmaxf(mloc, __shfl_xor(mloc, 32));
            const float m_new = fmaxf(m_run, mloc);

            // exp + pack PV B-frags directly (P stays in registers)
            float ssum = 0.0f;
            f16x8 pb[4];
            #pragma unroll
            for (int kp = 0; kp < 4; ++kp)
                #pragma unroll
                for (int e = 0; e < 8; ++e) {
                    const int reg = 8 * (kp & 1) + 4 * (e >> 2) + (e & 3);
                    const float sval = (kp < 2) ? s0[reg] : s1[reg];
                    const float p = exp2f(sval - m_new);     // exp2(-inf)=0
                    pb[kp][e] = (_Float16)p;
                    ssum += p;
                }
            ssum += __shfl_xor(ssum, 32);

            if (__all(m_new == m_run)) {         // exact defer (sc==1)
                l_run += ssum;
            } else {
                const float sc = exp2f(m_run - m_new);   // lane-local: one q/lane
                l_run = l_run * sc + ssum;
                m_run = m_new;
                #pragma unroll
                for (int dh = 0; dh < 2; ++dh)
                    #pragma unroll
                    for (int reg = 0; reg < 16; ++reg)
                        o[dh][reg] *= sc;
            }

            // ---- O^T += V^T . P^T   (A = Vt rows from LDS, B = pb registers)
            #pragma unroll
            for (int kp = 0; kp < 4; ++kp) {
                const int cc = 2 * kp + hi;
                #pragma unroll
                for (int dh = 0; dh < 2; ++dh) {
                    const int dr = 32 * dh + lo;
                    const f16x8 a = *(const f16x8*)(Vts + dr * 64 + ((cc ^ (dr & 7)) << 3));
                    o[dh] = __builtin_amdgcn_mfma_f32_32x32x16_f16(a, pb[kp], o[dh], 0, 0, 0);
                }
            }
        }

        __syncthreads();                 // B: group's LDS reads done
        if (nxtV) {                      // write staged regs
            #pragma unroll
            for (int t = 0; t < 4; ++t) {
                const int sr = 8 * (4 * qh + t) + srw;
                const int kr = SIG(sr);
                *(f16x8*)(Ks + kr * 64 + ((scc ^ (kr & 7)) << 3)) = kreg[t];
                *(f16x8*)(Vts + sr * 64 + ((scc ^ (sr & 7)) << 3)) = vreg[t];
            }
        }
    }

    // ---- 4-way merge through union over dead K/V LDS (58 KB <= 64 KB)
    float* OcF = (float*)smem;              // [(gid-1)*128 + qh*64 + l][36]
    float* ML  = (float*)smem + 13824;      // [((j*2+qh)*64 + lo)*2 + {m,l}]
    if (gid != 0) {
        float* dst = OcF + ((size_t)((gid - 1) * 128 + qh * 64 + l)) * 36;
        #pragma unroll
        for (int dh = 0; dh < 2; ++dh)
            #pragma unroll
            for (int u = 0; u < 4; ++u) {
                f32x4 v;
                #pragma unroll
                for (int e = 0; e < 4; ++e) v[e] = o[dh][4 * u + e];
                *(f32x4*)(dst + dh * 16 + 4 * u) = v;
            }
        if (hi == 0) {
            ML[(((gid - 1) * 2 + qh) * 64 + lo) * 2 + 0] = m_run;
            ML[(((gid - 1) * 2 + qh) * 64 + lo) * 2 + 1] = l_run;
        }
    }
    __syncthreads();

    if (gid == 0) {
        float mi[3], li[3];
        float mt = m_run;
        #pragma unroll
        for (int j = 0; j < 3; ++j) {
            mi[j] = ML[((j * 2 + qh) * 64 + lo) * 2 + 0];
            li[j] = ML[((j * 2 + qh) * 64 + lo) * 2 + 1];
            mt = fmaxf(mt, mi[j]);
        }
        const float c0 = exp2f(m_run - mt);
        float cj[3], den = l_run * c0;
        #pragma unroll
        for (int j = 0; j < 3; ++j) {
            cj[j] = exp2f(mi[j] - mt);          // empty group: mi=-1e30 -> 0
            den += li[j] * cj[j];
        }
        const float inv = 1.0f / den;           // group 0 always non-empty

        #pragma unroll
        for (int dh = 0; dh < 2; ++dh)
            #pragma unroll
            for (int u = 0; u < 4; ++u) {
                f16x4 outv;
                #pragma unroll
                for (int e = 0; e < 4; ++e) {
                    const int reg = 4 * u + e;
                    float val = o[dh][reg] * c0;
                    #pragma unroll
                    for (int j = 0; j < 3; ++j)
                        val += OcF[(size_t)(j * 128 + qh * 64 + l) * 36 + dh * 16 + reg] * cj[j];
                    outv[e] = (_Float16)(val * inv);
                }
                *(f16x4*)(AO + ((size_t)(b * LT) + qrow) * CC + h * DKH
                          + 32 * dh + 8 * u + 4 * hi) = outv;
            }
    }
    #undef TILE_OF
}

// ---------------------------------------------------------------------------
// Kernel 3: output projection, fp16 MFMA (X already f16), fp32 out.
// (R11 verbatim)
// ---------------------------------------------------------------------------
__global__ __launch_bounds__(256) void out_mfma(
    const f16* __restrict__ X, const float* __restrict__ Wo,
    const float* __restrict__ bo, float* __restrict__ Out)
{
    __shared__ f16 As[128 * 64];
    __shared__ f16 Bs[64 * 64];

    const int tid = threadIdx.x;
    const int w = tid >> 6, l = tid & 63;
    const int g = l >> 4, r = l & 15;

    const int m0 = blockIdx.x * 128;
    const int n0 = blockIdx.y * 64;

    f32x4 acc[2][4] = {};

    for (int k0 = 0; k0 < CC; k0 += 64) {
        #pragma unroll
        for (int m = 0; m < 4; ++m) {
            const int idx = m * 256 + tid;
            const int row = idx >> 3, c = idx & 7;
            *(f16x8*)(As + row * 64 + ((c ^ (row & 7)) << 3)) =
                *(const f16x8*)(X + (size_t)(m0 + row) * CC + k0 + c * 8);
        }
        #pragma unroll
        for (int m = 0; m < 2; ++m) {
            const int idx = m * 256 + tid;
            const int row = idx >> 3, c = idx & 7;
            const float* src = Wo + (size_t)(n0 + row) * CC + k0 + c * 8;
            const float4 x0 = *(const float4*)src;
            const float4 x1 = *(const float4*)(src + 4);
            *(f16x8*)(Bs + row * 64 + ((c ^ (row & 7)) << 3)) = cvt8(x0, x1);
        }
        __syncthreads();
        #pragma unroll
        for (int kc = 0; kc < 2; ++kc) {
            f16x8 af[2];
            #pragma unroll
            for (int i = 0; i < 2; ++i) {
                const int row = w * 32 + i * 16 + r;
                const int c = kc * 4 + g;
                af[i] = *(const f16x8*)(As + row * 64 + ((c ^ (row & 7)) << 3));
            }
            f16x8 bf[4];
            #pragma unroll
            for (int j = 0; j < 4; ++j) {
                const int row = j * 16 + r;
                const int c = kc * 4 + g;
                bf[j] = *(const f16x8*)(Bs + row * 64 + ((c ^ (row & 7)) << 3));
            }
            #pragma unroll
            for (int i = 0; i < 2; ++i)
                #pragma unroll
                for (int j = 0; j < 4; ++j)
                    acc[i][j] = __builtin_amdgcn_mfma_f32_16x16x32_f16(af[i], bf[j], acc[i][j], 0, 0, 0);
        }
        __syncthreads();
    }

    float bcol[4];
    #pragma unroll
    for (int j = 0; j < 4; ++j) bcol[j] = bo[n0 + j * 16 + r];

    #pragma unroll
    for (int i = 0; i < 2; ++i)
        #pragma unroll
        for (int e = 0; e < 4; ++e) {
            const int m = m0 + w * 32 + i * 16 + g * 4 + e;
            #pragma unroll
            for (int j = 0; j < 4; ++j)
                Out[(size_t)m * CC + n0 + j * 16 + r] = acc[i][j][e] + bcol[j];
        }
}

// ---------------------------------------------------------------------------
extern "C" void kernel_launch(void* const* d_in, const int* in_sizes, int n_in,
                              void* d_out, int out_size, void* d_ws, size_t ws_size,
                              hipStream_t stream)
{
    const float* audio = (const float*)d_in[0];
    const float* text  = (const float*)d_in[1];
    const int*   slen  = (const int*)d_in[2];
    const int*   tlen  = (const int*)d_in[3];
    const float* Wq = (const float*)d_in[4];
    const float* bq = (const float*)d_in[5];
    const float* Wk = (const float*)d_in[6];
    const float* bk = (const float*)d_in[7];
    const float* Wv = (const float*)d_in[8];
    const float* bv = (const float*)d_in[9];
    const float* Wo = (const float*)d_in[10];
    const float* bo = (const float*)d_in[11];
    float* out = (float*)d_out;

    f16* Qh  = (f16*)d_ws;
    f16* Kh  = Qh + SZ;
    f16* Vth = Kh + SZ;
    f16* AOh = Vth + SZ;

    qkv_mfma<<<dim3(64, 12), 256, 0, stream>>>(audio, text, Wq, bq, Wk, bk, Wv, bv,
                                               Qh, Kh, Vth);
    attn_f16<<<dim3(512), 512, 0, stream>>>(Qh, Kh, Vth, slen, tlen, AOh);
    out_mfma<<<dim3(64, 4), 256, 0, stream>>>(AOh, Wo, bo, out);
}

// Round 14
// 51.119 us; speedup vs baseline: 1.3283x; 1.3283x over previous
//
#include <hip/hip_runtime.h>
#include <hip/hip_bf16.h>
#include <math.h>

#define LA 1536
#define LS 512
#define LT 2048
#define CC 256
#define NH 4
#define DKH 64
#define NB 4
#define NT (LT / 64)
#define NTA (LA / 64)   // 24 audio tiles

// (1/sqrt(64)) * log2(e): softmax runs in exp2 domain, folded into Q at qkv
#define QSCALE 0.1803368801111244f

typedef _Float16 f16;
typedef __attribute__((ext_vector_type(8))) _Float16 f16x8;
typedef __attribute__((ext_vector_type(4))) _Float16 f16x4;
typedef __attribute__((ext_vector_type(4))) float f32x4;

__device__ inline f16x8 cvt8(const float4 a, const float4 b) {
    f16x8 h;
    h[0] = (_Float16)a.x; h[1] = (_Float16)a.y; h[2] = (_Float16)a.z; h[3] = (_Float16)a.w;
    h[4] = (_Float16)b.x; h[5] = (_Float16)b.y; h[6] = (_Float16)b.z; h[7] = (_Float16)b.w;
    return h;
}

// ---------------------------------------------------------------------------
// Kernel 1: fused QKV projection, fp16 MFMA, fp32 accumulate. (R12 + QSCALE
// folded into Q so attention softmax runs in the exp2 domain.)
// Q,K row-major f16; V transposed Vt[(b*NH+h)*DKH+d][l] via LDS transpose.
// ---------------------------------------------------------------------------
__global__ __launch_bounds__(256) void qkv_mfma(
    const float* __restrict__ audio, const float* __restrict__ text,
    const float* __restrict__ Wq, const float* __restrict__ bq,
    const float* __restrict__ Wk, const float* __restrict__ bk,
    const float* __restrict__ Wv, const float* __restrict__ bv,
    f16* __restrict__ Qh, f16* __restrict__ Kh, f16* __restrict__ Vth)
{
    __shared__ f16 smem[128 * 64 + 64 * 64];   // As | Bs ; reused as Ts for V
    f16* As = smem;
    f16* Bs = smem + 128 * 64;

    const int tid = threadIdx.x;
    const int w = tid >> 6, l = tid & 63;
    const int g = l >> 4, r = l & 15;

    const int m0 = blockIdx.x * 128;
    const int n0 = blockIdx.y * 64;
    const int mat = n0 >> 8;          // 0=Q 1=K 2=V
    const int ch0 = n0 & 255;

    const float* W    = (mat == 0) ? Wq : (mat == 1) ? Wk : Wv;
    const float* bias = (mat == 0) ? bq : (mat == 1) ? bk : bv;

    const int b  = m0 >> 11;
    const int l0 = m0 & 2047;         // 1536 % 128 == 0 -> clean split

    f32x4 acc[2][4] = {};

    for (int k0 = 0; k0 < CC; k0 += 64) {
        #pragma unroll
        for (int m = 0; m < 4; ++m) {
            const int idx = m * 256 + tid;
            const int row = idx >> 3, c = idx & 7;
            const int lrow = l0 + row;
            const float* src = (lrow < LA)
                ? (audio + ((size_t)b * LA + lrow) * CC + k0 + c * 8)
                : (text  + ((size_t)b * LS + (lrow - LA)) * CC + k0 + c * 8);
            const float4 x0 = *(const float4*)src;
            const float4 x1 = *(const float4*)(src + 4);
            *(f16x8*)(As + row * 64 + ((c ^ (row & 7)) << 3)) = cvt8(x0, x1);
        }
        #pragma unroll
        for (int m = 0; m < 2; ++m) {
            const int idx = m * 256 + tid;
            const int row = idx >> 3, c = idx & 7;
            const float* src = W + (size_t)(ch0 + row) * CC + k0 + c * 8;
            const float4 x0 = *(const float4*)src;
            const float4 x1 = *(const float4*)(src + 4);
            *(f16x8*)(Bs + row * 64 + ((c ^ (row & 7)) << 3)) = cvt8(x0, x1);
        }
        __syncthreads();
        #pragma unroll
        for (int kc = 0; kc < 2; ++kc) {
            f16x8 af[2];
            #pragma unroll
            for (int i = 0; i < 2; ++i) {
                const int row = w * 32 + i * 16 + r;
                const int c = kc * 4 + g;
                af[i] = *(const f16x8*)(As + row * 64 + ((c ^ (row & 7)) << 3));
            }
            f16x8 bf[4];
            #pragma unroll
            for (int j = 0; j < 4; ++j) {
                const int row = j * 16 + r;
                const int c = kc * 4 + g;
                bf[j] = *(const f16x8*)(Bs + row * 64 + ((c ^ (row & 7)) << 3));
            }
            #pragma unroll
            for (int i = 0; i < 2; ++i)
                #pragma unroll
                for (int j = 0; j < 4; ++j)
                    acc[i][j] = __builtin_amdgcn_mfma_f32_16x16x32_f16(af[i], bf[j], acc[i][j], 0, 0, 0);
        }
        __syncthreads();
    }

    float bcol[4];
    #pragma unroll
    for (int j = 0; j < 4; ++j) bcol[j] = bias[ch0 + j * 16 + r];

    if (mat <= 1) {
        f16* Out = (mat == 0) ? Qh : Kh;
        const float osc = (mat == 0) ? QSCALE : 1.0f;
        #pragma unroll
        for (int i = 0; i < 2; ++i)
            #pragma unroll
            for (int e = 0; e < 4; ++e) {
                const int m = m0 + w * 32 + i * 16 + g * 4 + e;
                #pragma unroll
                for (int j = 0; j < 4; ++j)
                    Out[(size_t)m * CC + ch0 + j * 16 + r] =
                        (_Float16)((acc[i][j][e] + bcol[j]) * osc);
            }
    } else {
        // V: stage C^T in LDS (Ts[64 n][136 m-pad]), then coalesced vec8 store.
        f16* Ts = smem;
        #pragma unroll
        for (int i = 0; i < 2; ++i)
            #pragma unroll
            for (int e = 0; e < 4; ++e) {
                const int ml = w * 32 + i * 16 + g * 4 + e;
                #pragma unroll
                for (int j = 0; j < 4; ++j)
                    Ts[(j * 16 + r) * 136 + ml] = (_Float16)(acc[i][j][e] + bcol[j]);
            }
        __syncthreads();
        const int b2 = m0 >> 11, l0m = m0 & 2047;
        #pragma unroll
        for (int u = 0; u < 4; ++u) {
            const int idx = u * 256 + tid;
            const int nl = idx >> 4, mc = idx & 15;
            const f16x8 vv = *(const f16x8*)(Ts + nl * 136 + mc * 8);
            const int nglob = ch0 + nl;
            const int hh = nglob >> 6, dd = nglob & 63;
            *(f16x8*)(Vth + ((size_t)((b2 * NH + hh) * DKH + dd)) * LT + l0m + mc * 8) = vv;
        }
    }
}

// ---------------------------------------------------------------------------
// Kernel 2: flash attention (R12 structure + XCD remap - the proven best) +
//  - exp2-domain softmax (QSCALE pre-folded into Q; exp2f = 1 v_exp, no mul)
//  - exact defer-rescale: __all(m_new==m_run) skips sc broadcast + o-rescale
//  - merge scratch (Oc 16KB + ML 1KB) aliased onto the dead K/V LDS buffers
//    (all tile reads complete before the loop's final barrier B) -> LDS 50KB
// Flat 1-D grid of 512: cmb = flat & 15 -> same-(b,h) blocks share an XCD
// (2 combos/XCD = 1 MB K/V per 4 MB L2); q-tile = flat >> 4.
// ---------------------------------------------------------------------------
__global__ __launch_bounds__(512) void attn_f16(
    const f16* __restrict__ Q, const f16* __restrict__ K,
    const f16* __restrict__ Vt,
    const int* __restrict__ slen, const int* __restrict__ tlen,
    f16* __restrict__ AO)
{
    __shared__ __align__(16) f16 Ks[2][4096];    // [group][key*64+d'], swizzled
    __shared__ __align__(16) f16 Vts[2][4096];   // [group][d*64+key'], swizzled
    __shared__ f16 Ps[8][16 * 72];               // per-wave P
    // merge overlays (used only after the loop, K/V tiles dead by then):
    float* OcF = (float*)&Ks[0][0];              // [wg*1024 + dsb*256 + lane4] 16KB
    float* MLf = (float*)&Vts[0][0];             // [(gid*64+qloc)*2 + {m,l}]  1KB

    const int tid = threadIdx.x;
    const int w = tid >> 6, l = tid & 63;
    const int gid = w >> 2, wg = w & 3;
    const int g = l >> 4, r = l & 15;
    const int tg = tid & 255;

    // ---- XCD-aware remap: combo fastest, q-tile slowest
    const int flat = blockIdx.x;
    const int cmb  = flat & 15;
    const int q0   = (flat >> 4) * 64;
    const int h    = cmb & 3;
    const int b    = cmb >> 2;

    const int ilen = slen[b];
    const int kcap = LA + tlen[b];
    const int nskip = ilen >> 6;
    int ntskip = 0;
    if (q0 >= LA) {
        const int skipmax = min(q0 - 63, kcap - 64);
        const int d = skipmax - LA;
        ntskip = (d < 0) ? 0 : ((d >> 6) + 1);
    }
    const int nAudio = NTA - nskip;
    const int nProc  = nAudio + (NT - NTA) - ntskip;
    const int nIter  = (nProc + 1) >> 1;

    const int qrow = q0 + 16 * wg + r;

    // Q fragment (QSCALE pre-folded by qkv_mfma -> exp2 domain)
    f16x8 qf[2];
    #pragma unroll
    for (int ch = 0; ch < 2; ++ch)
        qf[ch] = *(const f16x8*)(Q + ((size_t)(b * LT) + qrow) * CC + h * DKH + ch * 32 + g * 8);

    const int srow0 = tg >> 3, scc = tg & 7;
    const int srow1 = srow0 + 32;
    const int sdst0 = srow0 * 64 + ((scc ^ (srow0 & 7)) << 3);
    const int sdst1 = srow1 * 64 + ((scc ^ (srow1 & 7)) << 3);

    #define TILE_OF(p) ((p) < nAudio ? (nskip + (p)) : (NTA + ntskip + ((p) - nAudio)))

    {   // prologue
        const int k0 = TILE_OF(gid) * 64;
        *(f16x8*)(Ks[gid] + sdst0)  = *(const f16x8*)(K  + ((size_t)(b * LT) + k0 + srow0) * CC + h * DKH + scc * 8);
        *(f16x8*)(Vts[gid] + sdst0) = *(const f16x8*)(Vt + ((size_t)((b * NH + h) * DKH) + srow0) * LT + k0 + scc * 8);
        *(f16x8*)(Ks[gid] + sdst1)  = *(const f16x8*)(K  + ((size_t)(b * LT) + k0 + srow1) * CC + h * DKH + scc * 8);
        *(f16x8*)(Vts[gid] + sdst1) = *(const f16x8*)(Vt + ((size_t)((b * NH + h) * DKH) + srow1) * LT + k0 + scc * 8);
    }

    float m_run = -1e30f, l_run = 0.0f;
    f32x4 o[4] = {};

    for (int i = 0; i < nIter; ++i) {
        __syncthreads();                       // A: LDS tiles visible
        const int pcur = 2 * i + gid;
        const bool curV = pcur < nProc;
        const bool nxtV = (pcur + 2) < nProc;

        f16x8 kr0, vr0, kr1, vr1;
        if (nxtV) {
            const int kn = TILE_OF(pcur + 2) * 64;
            kr0 = *(const f16x8*)(K  + ((size_t)(b * LT) + kn + srow0) * CC + h * DKH + scc * 8);
            vr0 = *(const f16x8*)(Vt + ((size_t)((b * NH + h) * DKH) + srow0) * LT + kn + scc * 8);
            kr1 = *(const f16x8*)(K  + ((size_t)(b * LT) + kn + srow1) * CC + h * DKH + scc * 8);
            vr1 = *(const f16x8*)(Vt + ((size_t)((b * NH + h) * DKH) + srow1) * LT + kn + scc * 8);
        }

        if (curV) {
            const int kt = TILE_OF(pcur);
            const int k0 = kt * 64;

            f32x4 sacc[4] = {};
            #pragma unroll
            for (int s = 0; s < 4; ++s) {
                const int row = 16 * s + r;
                #pragma unroll
                for (int ch = 0; ch < 2; ++ch) {
                    const f16x8 a = *(const f16x8*)(Ks[gid] + row * 64 + ((((ch * 4 + g) ^ (row & 7)) & 7) << 3));
                    sacc[s] = __builtin_amdgcn_mfma_f32_16x16x32_f16(a, qf[ch], sacc[s], 0, 0, 0);
                }
            }

            const int mode = (kt < NTA) ? ((k0 >= ilen) ? 0 : 1)
                                        : ((q0 < LA) ? 0 : 2);
            float sv[16];
            if (mode == 0) {
                #pragma unroll
                for (int s = 0; s < 4; ++s)
                    #pragma unroll
                    for (int e = 0; e < 4; ++e) sv[s * 4 + e] = sacc[s][e];
            } else if (mode == 1) {
                #pragma unroll
                for (int s = 0; s < 4; ++s)
                    #pragma unroll
                    for (int e = 0; e < 4; ++e) {
                        const int kk = k0 + 16 * s + 4 * g + e;
                        sv[s * 4 + e] = (kk >= ilen) ? sacc[s][e] : -INFINITY;
                    }
            } else {
                #pragma unroll
                for (int s = 0; s < 4; ++s)
                    #pragma unroll
                    for (int e = 0; e < 4; ++e) {
                        const int kk = k0 + 16 * s + 4 * g + e;
                        sv[s * 4 + e] = (kk > qrow || kk >= kcap) ? sacc[s][e] : -INFINITY;
                    }
            }

            // ---- online softmax (exp2 domain, finite sentinel)
            float mloc = -1e30f;
            #pragma unroll
            for (int u = 0; u < 16; ++u) mloc = fmaxf(mloc, sv[u]);
            mloc = fmaxf(mloc, __shfl_xor(mloc, 16));
            mloc = fmaxf(mloc, __shfl_xor(mloc, 32));
            const float m_new = fmaxf(m_run, mloc);

            float ssum = 0.0f;
            f16x4 ph[4];
            #pragma unroll
            for (int s = 0; s < 4; ++s)
                #pragma unroll
                for (int e = 0; e < 4; ++e) {
                    const float p = exp2f(sv[s * 4 + e] - m_new);   // exp2(-inf)=0
                    ph[s][e] = (_Float16)p;
                    ssum += p;
                }
            ssum += __shfl_xor(ssum, 16);
            ssum += __shfl_xor(ssum, 32);

            if (__all(m_new == m_run)) {           // exact defer (sc == 1)
                l_run += ssum;
            } else {
                const float sc = exp2f(m_run - m_new);   // first live tile: 0
                l_run = l_run * sc + ssum;
                m_run = m_new;
                #pragma unroll
                for (int e = 0; e < 4; ++e) {
                    const float scr = __shfl(sc, 4 * g + e);
                    #pragma unroll
                    for (int dsb = 0; dsb < 4; ++dsb) o[dsb][e] *= scr;
                }
            }

            #pragma unroll
            for (int s = 0; s < 4; ++s)
                *(f16x4*)(&Ps[w][0] + r * 72 + 16 * s + 4 * g) = ph[s];

            #pragma unroll
            for (int ch = 0; ch < 2; ++ch) {
                const f16x8 a = *(const f16x8*)(&Ps[w][0] + r * 72 + ch * 32 + g * 8);
                #pragma unroll
                for (int dsb = 0; dsb < 4; ++dsb) {
                    const int vrow = 16 * dsb + r;
                    const f16x8 bf = *(const f16x8*)(Vts[gid] + vrow * 64 + ((((ch * 4 + g) ^ (vrow & 7)) & 7) << 3));
                    o[dsb] = __builtin_amdgcn_mfma_f32_16x16x32_f16(a, bf, o[dsb], 0, 0, 0);
                }
            }
        }

        __syncthreads();                       // B: group's LDS reads done
        if (nxtV) {
            *(f16x8*)(Ks[gid] + sdst0)  = kr0;
            *(f16x8*)(Vts[gid] + sdst0) = vr0;
            *(f16x8*)(Ks[gid] + sdst1)  = kr1;
            *(f16x8*)(Vts[gid] + sdst1) = vr1;
        }
    }

    // ---- combine the two groups' partials (overlays on dead K/V LDS).
    // All waves passed the loop's final barrier B; no further tile reads.
    if (g == 0) {
        MLf[(gid * 64 + 16 * wg + r) * 2 + 0] = m_run;
        MLf[(gid * 64 + 16 * wg + r) * 2 + 1] = l_run;
    }
    if (gid == 1) {
        #pragma unroll
        for (int dsb = 0; dsb < 4; ++dsb)
            *(f32x4*)(OcF + wg * 1024 + dsb * 256 + (g * 16 + r) * 4) = o[dsb];
    }
    __syncthreads();

    if (gid == 0) {
        #pragma unroll
        for (int e = 0; e < 4; ++e) {
            const int qloc = 16 * wg + 4 * g + e;
            const float m0v = MLf[(qloc) * 2 + 0],      l0v = MLf[(qloc) * 2 + 1];
            const float m1v = MLf[(64 + qloc) * 2 + 0], l1v = MLf[(64 + qloc) * 2 + 1];
            const float mt = fmaxf(m0v, m1v);
            const float c0 = exp2f(m0v - mt);
            const float c1 = exp2f(m1v - mt);
            const float inv = 1.0f / (l0v * c0 + l1v * c1);
            const int qq = q0 + qloc;
            #pragma unroll
            for (int dsb = 0; dsb < 4; ++dsb) {
                const float of = (o[dsb][e] * c0
                                + OcF[wg * 1024 + dsb * 256 + (g * 16 + r) * 4 + e] * c1) * inv;
                AO[((size_t)(b * LT) + qq) * CC + h * DKH + 16 * dsb + r] = (_Float16)of;
            }
        }
    }
    #undef TILE_OF
}

// ---------------------------------------------------------------------------
// Kernel 3: output projection, fp16 MFMA (X already f16), fp32 out. (R12)
// ---------------------------------------------------------------------------
__global__ __launch_bounds__(256) void out_mfma(
    const f16* __restrict__ X, const float* __restrict__ Wo,
    const float* __restrict__ bo, float* __restrict__ Out)
{
    __shared__ f16 As[128 * 64];
    __shared__ f16 Bs[64 * 64];

    const int tid = threadIdx.x;
    const int w = tid >> 6, l = tid & 63;
    const int g = l >> 4, r = l & 15;

    const int m0 = blockIdx.x * 128;
    const int n0 = blockIdx.y * 64;

    f32x4 acc[2][4] = {};

    for (int k0 = 0; k0 < CC; k0 += 64) {
        #pragma unroll
        for (int m = 0; m < 4; ++m) {
            const int idx = m * 256 + tid;
            const int row = idx >> 3, c = idx & 7;
            *(f16x8*)(As + row * 64 + ((c ^ (row & 7)) << 3)) =
                *(const f16x8*)(X + (size_t)(m0 + row) * CC + k0 + c * 8);
        }
        #pragma unroll
        for (int m = 0; m < 2; ++m) {
            const int idx = m * 256 + tid;
            const int row = idx >> 3, c = idx & 7;
            const float* src = Wo + (size_t)(n0 + row) * CC + k0 + c * 8;
            const float4 x0 = *(const float4*)src;
            const float4 x1 = *(const float4*)(src + 4);
            *(f16x8*)(Bs + row * 64 + ((c ^ (row & 7)) << 3)) = cvt8(x0, x1);
        }
        __syncthreads();
        #pragma unroll
        for (int kc = 0; kc < 2; ++kc) {
            f16x8 af[2];
            #pragma unroll
            for (int i = 0; i < 2; ++i) {
                const int row = w * 32 + i * 16 + r;
                const int c = kc * 4 + g;
                af[i] = *(const f16x8*)(As + row * 64 + ((c ^ (row & 7)) << 3));
            }
            f16x8 bf[4];
            #pragma unroll
            for (int j = 0; j < 4; ++j) {
                const int row = j * 16 + r;
                const int c = kc * 4 + g;
                bf[j] = *(const f16x8*)(Bs + row * 64 + ((c ^ (row & 7)) << 3));
            }
            #pragma unroll
            for (int i = 0; i < 2; ++i)
                #pragma unroll
                for (int j = 0; j < 4; ++j)
                    acc[i][j] = __builtin_amdgcn_mfma_f32_16x16x32_f16(af[i], bf[j], acc[i][j], 0, 0, 0);
        }
        __syncthreads();
    }

    float bcol[4];
    #pragma unroll
    for (int j = 0; j < 4; ++j) bcol[j] = bo[n0 + j * 16 + r];

    #pragma unroll
    for (int i = 0; i < 2; ++i)
        #pragma unroll
        for (int e = 0; e < 4; ++e) {
            const int m = m0 + w * 32 + i * 16 + g * 4 + e;
            #pragma unroll
            for (int j = 0; j < 4; ++j)
                Out[(size_t)m * CC + n0 + j * 16 + r] = acc[i][j][e] + bcol[j];
        }
}

// ---------------------------------------------------------------------------
extern "C" void kernel_launch(void* const* d_in, const int* in_sizes, int n_in,
                              void* d_out, int out_size, void* d_ws, size_t ws_size,
                              hipStream_t stream)
{
    const float* audio = (const float*)d_in[0];
    const float* text  = (const float*)d_in[1];
    const int*   slen  = (const int*)d_in[2];
    const int*   tlen  = (const int*)d_in[3];
    const float* Wq = (const float*)d_in[4];
    const float* bq = (const float*)d_in[5];
    const float* Wk = (const float*)d_in[6];
    const float* bk = (const float*)d_in[7];
    const float* Wv = (const float*)d_in[8];
    const float* bv = (const float*)d_in[9];
    const float* Wo = (const float*)d_in[10];
    const float* bo = (const float*)d_in[11];
    float* out = (float*)d_out;

    const size_t SZ = (size_t)NB * LT * CC;
    f16* Qh  = (f16*)d_ws;
    f16* Kh  = Qh + SZ;
    f16* Vth = Kh + SZ;
    f16* AOh = Vth + SZ;

    qkv_mfma<<<dim3(64, 12), 256, 0, stream>>>(audio, text, Wq, bq, Wk, bk, Wv, bv,
                                               Qh, Kh, Vth);
    attn_f16<<<dim3(512), 512, 0, stream>>>(Qh, Kh, Vth, slen, tlen, AOh);
    out_mfma<<<dim3(64, 4), 256, 0, stream>>>(AOh, Wo, bo, out);
}

// Round 15
// 47.851 us; speedup vs baseline: 1.4190x; 1.0683x over previous
//
#include <hip/hip_runtime.h>
#include <hip/hip_bf16.h>
#include <math.h>

#define LA 1536
#define LS 512
#define LT 2048
#define CC 256
#define NH 4
#define DKH 64
#define NB 4
#define NT (LT / 64)
#define NTA (LA / 64)   // 24 audio tiles

typedef _Float16 f16;
typedef __attribute__((ext_vector_type(8))) _Float16 f16x8;
typedef __attribute__((ext_vector_type(4))) _Float16 f16x4;
typedef __attribute__((ext_vector_type(4))) float f32x4;

__device__ inline f16x8 cvt8(const float4 a, const float4 b) {
    f16x8 h;
    h[0] = (_Float16)a.x; h[1] = (_Float16)a.y; h[2] = (_Float16)a.z; h[3] = (_Float16)a.w;
    h[4] = (_Float16)b.x; h[5] = (_Float16)b.y; h[6] = (_Float16)b.z; h[7] = (_Float16)b.w;
    return h;
}

// ---------------------------------------------------------------------------
// Kernel 1: fused QKV projection, fp16 MFMA, fp32 accumulate. (R4 verbatim)
// Q,K row-major f16; V transposed Vt[(b*NH+h)*DKH+d][l] via LDS transpose.
// ---------------------------------------------------------------------------
__global__ __launch_bounds__(256) void qkv_mfma(
    const float* __restrict__ audio, const float* __restrict__ text,
    const float* __restrict__ Wq, const float* __restrict__ bq,
    const float* __restrict__ Wk, const float* __restrict__ bk,
    const float* __restrict__ Wv, const float* __restrict__ bv,
    f16* __restrict__ Qh, f16* __restrict__ Kh, f16* __restrict__ Vth)
{
    __shared__ f16 smem[128 * 64 + 64 * 64];   // As | Bs ; reused as Ts for V
    f16* As = smem;
    f16* Bs = smem + 128 * 64;

    const int tid = threadIdx.x;
    const int w = tid >> 6, l = tid & 63;
    const int g = l >> 4, r = l & 15;

    const int m0 = blockIdx.x * 128;
    const int n0 = blockIdx.y * 64;
    const int mat = n0 >> 8;          // 0=Q 1=K 2=V
    const int ch0 = n0 & 255;

    const float* W    = (mat == 0) ? Wq : (mat == 1) ? Wk : Wv;
    const float* bias = (mat == 0) ? bq : (mat == 1) ? bk : bv;

    const int b  = m0 >> 11;
    const int l0 = m0 & 2047;         // 1536 % 128 == 0 -> clean split

    f32x4 acc[2][4] = {};

    for (int k0 = 0; k0 < CC; k0 += 64) {
        #pragma unroll
        for (int m = 0; m < 4; ++m) {
            const int idx = m * 256 + tid;
            const int row = idx >> 3, c = idx & 7;
            const int lrow = l0 + row;
            const float* src = (lrow < LA)
                ? (audio + ((size_t)b * LA + lrow) * CC + k0 + c * 8)
                : (text  + ((size_t)b * LS + (lrow - LA)) * CC + k0 + c * 8);
            const float4 x0 = *(const float4*)src;
            const float4 x1 = *(const float4*)(src + 4);
            *(f16x8*)(As + row * 64 + ((c ^ (row & 7)) << 3)) = cvt8(x0, x1);
        }
        #pragma unroll
        for (int m = 0; m < 2; ++m) {
            const int idx = m * 256 + tid;
            const int row = idx >> 3, c = idx & 7;
            const float* src = W + (size_t)(ch0 + row) * CC + k0 + c * 8;
            const float4 x0 = *(const float4*)src;
            const float4 x1 = *(const float4*)(src + 4);
            *(f16x8*)(Bs + row * 64 + ((c ^ (row & 7)) << 3)) = cvt8(x0, x1);
        }
        __syncthreads();
        #pragma unroll
        for (int kc = 0; kc < 2; ++kc) {
            f16x8 af[2];
            #pragma unroll
            for (int i = 0; i < 2; ++i) {
                const int row = w * 32 + i * 16 + r;
                const int c = kc * 4 + g;
                af[i] = *(const f16x8*)(As + row * 64 + ((c ^ (row & 7)) << 3));
            }
            f16x8 bf[4];
            #pragma unroll
            for (int j = 0; j < 4; ++j) {
                const int row = j * 16 + r;
                const int c = kc * 4 + g;
                bf[j] = *(const f16x8*)(Bs + row * 64 + ((c ^ (row & 7)) << 3));
            }
            #pragma unroll
            for (int i = 0; i < 2; ++i)
                #pragma unroll
                for (int j = 0; j < 4; ++j)
                    acc[i][j] = __builtin_amdgcn_mfma_f32_16x16x32_f16(af[i], bf[j], acc[i][j], 0, 0, 0);
        }
        __syncthreads();
    }

    float bcol[4];
    #pragma unroll
    for (int j = 0; j < 4; ++j) bcol[j] = bias[ch0 + j * 16 + r];

    if (mat <= 1) {
        f16* Out = (mat == 0) ? Qh : Kh;
        #pragma unroll
        for (int i = 0; i < 2; ++i)
            #pragma unroll
            for (int e = 0; e < 4; ++e) {
                const int m = m0 + w * 32 + i * 16 + g * 4 + e;
                #pragma unroll
                for (int j = 0; j < 4; ++j)
                    Out[(size_t)m * CC + ch0 + j * 16 + r] = (_Float16)(acc[i][j][e] + bcol[j]);
            }
    } else {
        // V: stage C^T in LDS (Ts[64 n][136 m-pad]), then coalesced vec8 store.
        f16* Ts = smem;
        #pragma unroll
        for (int i = 0; i < 2; ++i)
            #pragma unroll
            for (int e = 0; e < 4; ++e) {
                const int ml = w * 32 + i * 16 + g * 4 + e;
                #pragma unroll
                for (int j = 0; j < 4; ++j)
                    Ts[(j * 16 + r) * 136 + ml] = (_Float16)(acc[i][j][e] + bcol[j]);
            }
        __syncthreads();
        const int b2 = m0 >> 11, l0m = m0 & 2047;
        #pragma unroll
        for (int u = 0; u < 4; ++u) {
            const int idx = u * 256 + tid;
            const int nl = idx >> 4, mc = idx & 15;
            const f16x8 vv = *(const f16x8*)(Ts + nl * 136 + mc * 8);
            const int nglob = ch0 + nl;
            const int hh = nglob >> 6, dd = nglob & 63;
            *(f16x8*)(Vth + ((size_t)((b2 * NH + hh) * DKH + dd)) * LT + l0m + mc * 8) = vv;
        }
    }
}

// ---------------------------------------------------------------------------
// Kernel 2: flash attention (R4 structure) + XCD-AWARE BLOCK REMAP (T1).
// Flat 1-D grid of 512: c = flat & 15 selects (b,h), x = flat >> 4 selects
// q-tile. Under round-robin XCD dispatch (d % 8), all 32 q-blocks of one
// (b,h) land on ONE XCD -> its 512 KB K/V stays L2-resident (2 combos/XCD
// = 1 MB in 4 MB L2). Measured: FETCH 74 MB -> 38 MB (R13 counters).
// ---------------------------------------------------------------------------
__global__ __launch_bounds__(512) void attn_f16(
    const f16* __restrict__ Q, const f16* __restrict__ K,
    const f16* __restrict__ Vt,
    const int* __restrict__ slen, const int* __restrict__ tlen,
    f16* __restrict__ AO)
{
    __shared__ f16 Ks[2][4096];       // [group][key*64+d'], swizzled
    __shared__ f16 Vts[2][4096];      // [group][d*64+key'], swizzled
    __shared__ f16 Ps[8][16 * 72];    // per-wave P
    __shared__ float Oc[4][1024];     // group-1 o
    __shared__ float ML[2][64][2];    // [group][q_local][m,l]

    const int tid = threadIdx.x;
    const int w = tid >> 6, l = tid & 63;
    const int gid = w >> 2, wg = w & 3;
    const int g = l >> 4, r = l & 15;
    const int tg = tid & 255;

    // ---- XCD-aware remap: combo fastest, q-tile slowest
    const int flat = blockIdx.x;
    const int cmb  = flat & 15;        // (b,h) combo: same-combo blocks share XCD
    const int q0   = (flat >> 4) * 64;
    const int h    = cmb & 3;
    const int b    = cmb >> 2;

    const int ilen = slen[b];
    const int kcap = LA + tlen[b];
    const int nskip = ilen >> 6;
    int ntskip = 0;
    if (q0 >= LA) {
        const int skipmax = min(q0 - 63, kcap - 64);
        const int d = skipmax - LA;
        ntskip = (d < 0) ? 0 : ((d >> 6) + 1);
    }
    const int nAudio = NTA - nskip;
    const int nProc  = nAudio + (NT - NTA) - ntskip;
    const int nIter  = (nProc + 1) >> 1;

    const int qrow = q0 + 16 * wg + r;

    f16x8 qf[2];
    #pragma unroll
    for (int ch = 0; ch < 2; ++ch) {
        f16x8 q8 = *(const f16x8*)(Q + ((size_t)(b * LT) + qrow) * CC + h * DKH + ch * 32 + g * 8);
        #pragma unroll
        for (int e = 0; e < 8; ++e) q8[e] = q8[e] * (_Float16)0.125f;
        qf[ch] = q8;
    }

    const int srow0 = tg >> 3, scc = tg & 7;
    const int srow1 = srow0 + 32;
    const int sdst0 = srow0 * 64 + ((scc ^ (srow0 & 7)) << 3);
    const int sdst1 = srow1 * 64 + ((scc ^ (srow1 & 7)) << 3);

    #define TILE_OF(p) ((p) < nAudio ? (nskip + (p)) : (NTA + ntskip + ((p) - nAudio)))

    {   // prologue
        const int k0 = TILE_OF(gid) * 64;
        *(f16x8*)(Ks[gid] + sdst0)  = *(const f16x8*)(K  + ((size_t)(b * LT) + k0 + srow0) * CC + h * DKH + scc * 8);
        *(f16x8*)(Vts[gid] + sdst0) = *(const f16x8*)(Vt + ((size_t)((b * NH + h) * DKH) + srow0) * LT + k0 + scc * 8);
        *(f16x8*)(Ks[gid] + sdst1)  = *(const f16x8*)(K  + ((size_t)(b * LT) + k0 + srow1) * CC + h * DKH + scc * 8);
        *(f16x8*)(Vts[gid] + sdst1) = *(const f16x8*)(Vt + ((size_t)((b * NH + h) * DKH) + srow1) * LT + k0 + scc * 8);
    }

    float m_run = -1e30f, l_run = 0.0f;
    f32x4 o[4] = {};

    for (int i = 0; i < nIter; ++i) {
        __syncthreads();                       // A: LDS tiles visible
        const int pcur = 2 * i + gid;
        const bool curV = pcur < nProc;
        const bool nxtV = (pcur + 2) < nProc;

        f16x8 kr0, vr0, kr1, vr1;
        if (nxtV) {
            const int kn = TILE_OF(pcur + 2) * 64;
            kr0 = *(const f16x8*)(K  + ((size_t)(b * LT) + kn + srow0) * CC + h * DKH + scc * 8);
            vr0 = *(const f16x8*)(Vt + ((size_t)((b * NH + h) * DKH) + srow0) * LT + kn + scc * 8);
            kr1 = *(const f16x8*)(K  + ((size_t)(b * LT) + kn + srow1) * CC + h * DKH + scc * 8);
            vr1 = *(const f16x8*)(Vt + ((size_t)((b * NH + h) * DKH) + srow1) * LT + kn + scc * 8);
        }

        if (curV) {
            const int kt = TILE_OF(pcur);
            const int k0 = kt * 64;

            f32x4 sacc[4] = {};
            #pragma unroll
            for (int s = 0; s < 4; ++s) {
                const int row = 16 * s + r;
                #pragma unroll
                for (int ch = 0; ch < 2; ++ch) {
                    const f16x8 a = *(const f16x8*)(Ks[gid] + row * 64 + ((((ch * 4 + g) ^ (row & 7)) & 7) << 3));
                    sacc[s] = __builtin_amdgcn_mfma_f32_16x16x32_f16(a, qf[ch], sacc[s], 0, 0, 0);
                }
            }

            const int mode = (kt < NTA) ? ((k0 >= ilen) ? 0 : 1)
                                        : ((q0 < LA) ? 0 : 2);
            float sv[16];
            if (mode == 0) {
                #pragma unroll
                for (int s = 0; s < 4; ++s)
                    #pragma unroll
                    for (int e = 0; e < 4; ++e) sv[s * 4 + e] = sacc[s][e];
            } else if (mode == 1) {
                #pragma unroll
                for (int s = 0; s < 4; ++s)
                    #pragma unroll
                    for (int e = 0; e < 4; ++e) {
                        const int kk = k0 + 16 * s + 4 * g + e;
                        sv[s * 4 + e] = (kk >= ilen) ? sacc[s][e] : -INFINITY;
                    }
            } else {
                #pragma unroll
                for (int s = 0; s < 4; ++s)
                    #pragma unroll
                    for (int e = 0; e < 4; ++e) {
                        const int kk = k0 + 16 * s + 4 * g + e;
                        sv[s * 4 + e] = (kk > qrow || kk >= kcap) ? sacc[s][e] : -INFINITY;
                    }
            }

            float mloc = -1e30f;
            #pragma unroll
            for (int u = 0; u < 16; ++u) mloc = fmaxf(mloc, sv[u]);
            mloc = fmaxf(mloc, __shfl_xor(mloc, 16));
            mloc = fmaxf(mloc, __shfl_xor(mloc, 32));
            const float m_new = fmaxf(m_run, mloc);

            float ssum = 0.0f;
            f16x4 ph[4];
            #pragma unroll
            for (int s = 0; s < 4; ++s)
                #pragma unroll
                for (int e = 0; e < 4; ++e) {
                    const float p = __expf(sv[s * 4 + e] - m_new);
                    ph[s][e] = (_Float16)p;
                    ssum += p;
                }
            ssum += __shfl_xor(ssum, 16);
            ssum += __shfl_xor(ssum, 32);
            const float sc = __expf(m_run - m_new);
            l_run = l_run * sc + ssum;
            m_run = m_new;

            #pragma unroll
            for (int s = 0; s < 4; ++s)
                *(f16x4*)(&Ps[w][0] + r * 72 + 16 * s + 4 * g) = ph[s];

            #pragma unroll
            for (int e = 0; e < 4; ++e) {
                const float scr = __shfl(sc, 4 * g + e);
                #pragma unroll
                for (int dsb = 0; dsb < 4; ++dsb) o[dsb][e] *= scr;
            }

            #pragma unroll
            for (int ch = 0; ch < 2; ++ch) {
                const f16x8 a = *(const f16x8*)(&Ps[w][0] + r * 72 + ch * 32 + g * 8);
                #pragma unroll
                for (int dsb = 0; dsb < 4; ++dsb) {
                    const int vrow = 16 * dsb + r;
                    const f16x8 bf = *(const f16x8*)(Vts[gid] + vrow * 64 + ((((ch * 4 + g) ^ (vrow & 7)) & 7) << 3));
                    o[dsb] = __builtin_amdgcn_mfma_f32_16x16x32_f16(a, bf, o[dsb], 0, 0, 0);
                }
            }
        }

        __syncthreads();                       // B: group's LDS reads done
        if (nxtV) {
            *(f16x8*)(Ks[gid] + sdst0)  = kr0;
            *(f16x8*)(Vts[gid] + sdst0) = vr0;
            *(f16x8*)(Ks[gid] + sdst1)  = kr1;
            *(f16x8*)(Vts[gid] + sdst1) = vr1;
        }
    }

    // ---- combine the two groups' partials
    if (g == 0) {
        ML[gid][16 * wg + r][0] = m_run;
        ML[gid][16 * wg + r][1] = l_run;
    }
    if (gid == 1) {
        #pragma unroll
        for (int dsb = 0; dsb < 4; ++dsb)
            *(f32x4*)&Oc[wg][dsb * 256 + (g * 16 + r) * 4] = o[dsb];
    }
    __syncthreads();

    if (gid == 0) {
        #pragma unroll
        for (int e = 0; e < 4; ++e) {
            const int qloc = 16 * wg + 4 * g + e;
            const float m0v = ML[0][qloc][0], l0v = ML[0][qloc][1];
            const float m1v = ML[1][qloc][0], l1v = ML[1][qloc][1];
            const float mt = fmaxf(m0v, m1v);
            const float c0 = __expf(m0v - mt);
            const float c1 = __expf(m1v - mt);
            const float inv = 1.0f / (l0v * c0 + l1v * c1);
            const int qq = q0 + qloc;
            #pragma unroll
            for (int dsb = 0; dsb < 4; ++dsb) {
                const float of = (o[dsb][e] * c0 + Oc[wg][dsb * 256 + (g * 16 + r) * 4 + e] * c1) * inv;
                AO[((size_t)(b * LT) + qq) * CC + h * DKH + 16 * dsb + r] = (_Float16)of;
            }
        }
    }
    #undef TILE_OF
}

// ---------------------------------------------------------------------------
// Kernel 3: output projection, fp16 MFMA (X already f16), fp32 out. (R4)
// ---------------------------------------------------------------------------
__global__ __launch_bounds__(256) void out_mfma(
    const f16* __restrict__ X, const float* __restrict__ Wo,
    const float* __restrict__ bo, float* __restrict__ Out)
{
    __shared__ f16 As[128 * 64];
    __shared__ f16 Bs[64 * 64];

    const int tid = threadIdx.x;
    const int w = tid >> 6, l = tid & 63;
    const int g = l >> 4, r = l & 15;

    const int m0 = blockIdx.x * 128;
    const int n0 = blockIdx.y * 64;

    f32x4 acc[2][4] = {};

    for (int k0 = 0; k0 < CC; k0 += 64) {
        #pragma unroll
        for (int m = 0; m < 4; ++m) {
            const int idx = m * 256 + tid;
            const int row = idx >> 3, c = idx & 7;
            *(f16x8*)(As + row * 64 + ((c ^ (row & 7)) << 3)) =
                *(const f16x8*)(X + (size_t)(m0 + row) * CC + k0 + c * 8);
        }
        #pragma unroll
        for (int m = 0; m < 2; ++m) {
            const int idx = m * 256 + tid;
            const int row = idx >> 3, c = idx & 7;
            const float* src = Wo + (size_t)(n0 + row) * CC + k0 + c * 8;
            const float4 x0 = *(const float4*)src;
            const float4 x1 = *(const float4*)(src + 4);
            *(f16x8*)(Bs + row * 64 + ((c ^ (row & 7)) << 3)) = cvt8(x0, x1);
        }
        __syncthreads();
        #pragma unroll
        for (int kc = 0; kc < 2; ++kc) {
            f16x8 af[2];
            #pragma unroll
            for (int i = 0; i < 2; ++i) {
                const int row = w * 32 + i * 16 + r;
                const int c = kc * 4 + g;
                af[i] = *(const f16x8*)(As + row * 64 + ((c ^ (row & 7)) << 3));
            }
            f16x8 bf[4];
            #pragma unroll
            for (int j = 0; j < 4; ++j) {
                const int row = j * 16 + r;
                const int c = kc * 4 + g;
                bf[j] = *(const f16x8*)(Bs + row * 64 + ((c ^ (row & 7)) << 3));
            }
            #pragma unroll
            for (int i = 0; i < 2; ++i)
                #pragma unroll
                for (int j = 0; j < 4; ++j)
                    acc[i][j] = __builtin_amdgcn_mfma_f32_16x16x32_f16(af[i], bf[j], acc[i][j], 0, 0, 0);
        }
        __syncthreads();
    }

    float bcol[4];
    #pragma unroll
    for (int j = 0; j < 4; ++j) bcol[j] = bo[n0 + j * 16 + r];

    #pragma unroll
    for (int i = 0; i < 2; ++i)
        #pragma unroll
        for (int e = 0; e < 4; ++e) {
            const int m = m0 + w * 32 + i * 16 + g * 4 + e;
            #pragma unroll
            for (int j = 0; j < 4; ++j)
                Out[(size_t)m * CC + n0 + j * 16 + r] = acc[i][j][e] + bcol[j];
        }
}

// ---------------------------------------------------------------------------
extern "C" void kernel_launch(void* const* d_in, const int* in_sizes, int n_in,
                              void* d_out, int out_size, void* d_ws, size_t ws_size,
                              hipStream_t stream)
{
    const float* audio = (const float*)d_in[0];
    const float* text  = (const float*)d_in[1];
    const int*   slen  = (const int*)d_in[2];
    const int*   tlen  = (const int*)d_in[3];
    const float* Wq = (const float*)d_in[4];
    const float* bq = (const float*)d_in[5];
    const float* Wk = (const float*)d_in[6];
    const float* bk = (const float*)d_in[7];
    const float* Wv = (const float*)d_in[8];
    const float* bv = (const float*)d_in[9];
    const float* Wo = (const float*)d_in[10];
    const float* bo = (const float*)d_in[11];
    float* out = (float*)d_out;

    const size_t SZ = (size_t)NB * LT * CC;
    f16* Qh  = (f16*)d_ws;
    f16* Kh  = Qh + SZ;
    f16* Vth = Kh + SZ;
    f16* AOh = Vth + SZ;

    qkv_mfma<<<dim3(64, 12), 256, 0, stream>>>(audio, text, Wq, bq, Wk, bk, Wv, bv,
                                               Qh, Kh, Vth);
    attn_f16<<<dim3(512), 512, 0, stream>>>(Qh, Kh, Vth, slen, tlen, AOh);
    out_mfma<<<dim3(64, 4), 256, 0, stream>>>(AOh, Wo, bo, out);
}